// Round 1
// baseline (1671.345 us; speedup 1.0000x reference)
//
#include <hip/hip_runtime.h>
#include <hip/hip_bf16.h>

// QLinear int4-dequant GEMM: C[8192,11008] = X[8192,4096](fp32) @ deq(W)[4096,11008]
// v2: split into (a) X fp32->bf16 convert, (b) W int4->bf16 dequant to [n][k],
//     (c) m97-structure bf16 GEMM: 128x128 tile, BK=32, global_load_lds width-16
//     staging (DMA, no VALU), double-buffered LDS, XOR-swizzled frag layout.
// Rationale: previous fused kernel was VALU-bound (VALUBusy 65% vs MfmaUtil 33%)
// re-dequantizing W 64x and re-converting X 86x inside the GEMM inner loop.

#define K_DIM 4096
#define N_DIM 11008
#define M_DIM 8192
#define BK 32

typedef unsigned short u16;
typedef __attribute__((ext_vector_type(8))) short short8;       // 8 x bf16 MFMA A/B frag
typedef __attribute__((ext_vector_type(4))) float f32x4;        // MFMA C/D frag / float4
typedef __attribute__((ext_vector_type(4))) unsigned int u32x4; // 16B store of 8 bf16

__device__ __forceinline__ unsigned cvt2(float a, float b) {
    __hip_bfloat162 h = __float22bfloat162_rn(make_float2(a, b));
    unsigned u;
    __builtin_memcpy(&u, &h, 4);
    return u;
}

#define GLOAD_LDS16(g, l)                                                 \
    __builtin_amdgcn_global_load_lds(                                     \
        (const __attribute__((address_space(1))) unsigned int*)(g),       \
        (__attribute__((address_space(3))) unsigned int*)(l), 16, 0, 0)

// ---------------------------------------------------------------------------
// Pre-pass 1: X fp32 -> bf16. 8 floats/thread, fully coalesced.
__global__ __launch_bounds__(256) void xcvt(const float* __restrict__ X,
                                            u16* __restrict__ Xb) {
    const size_t i = ((size_t)blockIdx.x * 256 + threadIdx.x) * 8;
    f32x4 a = *(const f32x4*)(X + i);
    f32x4 b = *(const f32x4*)(X + i + 4);
    u32x4 v;
    v[0] = cvt2(a[0], a[1]);
    v[1] = cvt2(a[2], a[3]);
    v[2] = cvt2(b[0], b[1]);
    v[3] = cvt2(b[2], b[3]);
    *(u32x4*)(Xb + i) = v;
}

// ---------------------------------------------------------------------------
// Pre-pass 2: W int4 -> bf16, layout Wt[n][k] (k-contiguous, GEMM B^T form).
// thread (t&7)=kw-offset, (t>>3)=n-offset: writes are 8 contiguous 128B rows/wave.
__global__ __launch_bounds__(256) void wdeq(const int* __restrict__ Q,
                                            const float* __restrict__ SC,
                                            const float* __restrict__ ZP,
                                            u16* __restrict__ Wt) {
    const int t  = threadIdx.x;
    const int n  = blockIdx.x * 32 + (t >> 3);
    const int kw = blockIdx.y * 8 + (t & 7);
    const unsigned w = (unsigned)Q[(size_t)kw * N_DIM + n];
    const float sc  = SC[n];
    const float nzs = -ZP[n] * sc;  // exact affine: (float)nib * sc + nzs
    float f[8];
#pragma unroll
    for (int j = 0; j < 8; ++j)  // k = kw*8 + j, nibble j at bits [28-4j..31-4j]
        f[j] = fmaf((float)((w >> (28 - 4 * j)) & 15u), sc, nzs);
    u32x4 v;
    v[0] = cvt2(f[0], f[1]);
    v[1] = cvt2(f[2], f[3]);
    v[2] = cvt2(f[4], f[5]);
    v[3] = cvt2(f[6], f[7]);
    *(u32x4*)(Wt + (size_t)n * K_DIM + kw * 8) = v;
}

// ---------------------------------------------------------------------------
// Main GEMM: m97 structure. 128x128 tile, BK=32, 256 thr (4 waves 2x2),
// per-wave 4x4 frags of mfma_f32_16x16x32_bf16. global_load_lds DMA staging
// (linear LDS dest, pre-swizzled global source), XOR swizzle c' = c ^ ((row>>1)&3)
// on 16B units so frag ds_read_b128 is <=2-way banked (free).
__global__ __launch_bounds__(256, 3) void qgemm_main(const u16* __restrict__ Ab,
                                                     const u16* __restrict__ Bt,
                                                     float* __restrict__ C) {
    __shared__ u16 As[2][128 * BK];
    __shared__ u16 Bs[2][128 * BK];

    const int tid  = threadIdx.x;
    const int lane = tid & 63;
    const int wave = tid >> 6;
    const int m0 = blockIdx.y * 128;
    const int n0 = blockIdx.x * 128;

    // Staging map: LDS 16B-unit u = tid holds global (row = u>>2, k8 = (u&3)^((u>>3)&3)).
    // (u>>3)&3 == (row>>1)&3 for c<4, so LDS[row][c] holds global k8 = c ^ ((row>>1)&3).
    const int srow = tid >> 2;                        // 0..63 (+64 on 2nd issue)
    const int sk8  = (tid & 3) ^ ((tid >> 3) & 3);    // swizzled source 16B-unit
    const u16* ga0 = Ab + (size_t)(m0 + srow) * K_DIM + sk8 * 8;
    const u16* ga1 = ga0 + (size_t)64 * K_DIM;
    const u16* gb0 = Bt + (size_t)(n0 + srow) * K_DIM + sk8 * 8;
    const u16* gb1 = gb0 + (size_t)64 * K_DIM;

    auto stage = [&](int buf, int kt) {
        u16* la = &As[buf][tid * 8];   // dest = wave-uniform base + lane*16 (linear)
        u16* lb = &Bs[buf][tid * 8];
        GLOAD_LDS16(ga0 + kt, la);
        GLOAD_LDS16(ga1 + kt, la + 2048);  // rows 64..127 at +4096B
        GLOAD_LDS16(gb0 + kt, lb);
        GLOAD_LDS16(gb1 + kt, lb + 2048);
    };

    // Fragment read addressing (swizzle term constant across i*16 row steps):
    const int wm = (wave >> 1) * 64;
    const int wn = (wave & 1) * 64;
    const int fr = lane & 15;
    const int fq = lane >> 4;
    const int sw = (fr >> 1) & 3;
    const int aoff = (wm + fr) * BK + (fq ^ sw) * 8;
    const int boff = (wn + fr) * BK + (fq ^ sw) * 8;

    f32x4 acc[4][4] = {};

    stage(0, 0);
    __syncthreads();   // drains vmcnt(0): buf0 ready

    int cur = 0;
    for (int kt = 0;;) {
        const int knext = kt + BK;
        const bool last = (knext >= K_DIM);
        if (!last) stage(cur ^ 1, knext);  // async DMA overlaps this tile's compute

        const u16* Ap = &As[cur][aoff];
        const u16* Bp = &Bs[cur][boff];
        short8 af[4], bf[4];
#pragma unroll
        for (int i = 0; i < 4; ++i) {
            af[i] = *(const short8*)(Ap + i * 16 * BK);
            bf[i] = *(const short8*)(Bp + i * 16 * BK);
        }
#pragma unroll
        for (int mi = 0; mi < 4; ++mi)
#pragma unroll
            for (int ni = 0; ni < 4; ++ni)
                acc[mi][ni] = __builtin_amdgcn_mfma_f32_16x16x32_bf16(
                    af[mi], bf[ni], acc[mi][ni], 0, 0, 0);

        if (last) break;
        __syncthreads();  // drains vmcnt(0)+lgkmcnt(0): next buf ready, reads done
        cur ^= 1;
        kt = knext;
    }

    // Epilogue: C/D layout col=lane&15, row=fq*4+r (m89/m91-verified)
#pragma unroll
    for (int mi = 0; mi < 4; ++mi) {
#pragma unroll
        for (int ni = 0; ni < 4; ++ni) {
            const int row = m0 + wm + mi * 16 + fq * 4;
            const int col = n0 + wn + ni * 16 + fr;
            float* cp = C + (size_t)row * N_DIM + col;
#pragma unroll
            for (int r = 0; r < 4; ++r)
                cp[(size_t)r * N_DIM] = acc[mi][ni][r];
        }
    }
}

// ---------------------------------------------------------------------------
// Fallback (previous verified kernel) for the case ws_size < 157.3 MB.
#define LDA 40
__global__ __launch_bounds__(256, 3) void qgemm_fused(
    const float* __restrict__ X, const int* __restrict__ Q,
    const float* __restrict__ SC, const float* __restrict__ ZP,
    float* __restrict__ C)
{
    __shared__ short As[128 * LDA];
    __shared__ short Bs[128 * LDA];

    const int tid  = threadIdx.x;
    const int lane = tid & 63;
    const int wave = tid >> 6;

    const int m0 = blockIdx.y * 128;
    const int n0 = blockIdx.x * 128;

    const int arow = tid >> 2;
    const int ak8  = (tid & 3) * 8;
    const float* xbase = X + (size_t)(m0 + arow) * K_DIM + ak8;

    const int bcol  = tid & 127;
    const int brow0 = tid >> 7;
    const int* qbase = Q + (size_t)brow0 * N_DIM + n0 + bcol;
    const float sc  = SC[n0 + bcol];
    const float nzs = -ZP[n0 + bcol] * sc;

    f32x4 areg[4];
    int   breg[2];

    auto load_tile = [&](int kt) {
        const float* p0 = xbase + kt;
        areg[0] = *(const f32x4*)(p0);
        areg[1] = *(const f32x4*)(p0 + 4);
        const float* p1 = p0 + (size_t)64 * K_DIM;
        areg[2] = *(const f32x4*)(p1);
        areg[3] = *(const f32x4*)(p1 + 4);
        const int* q0 = qbase + (size_t)(kt >> 3) * N_DIM;
        breg[0] = q0[0];
        breg[1] = q0[2 * N_DIM];
    };

    auto store_tile = [&]() {
        #pragma unroll
        for (int p = 0; p < 2; ++p) {
            u32x4 v;
            v[0] = cvt2(areg[2*p+0][0], areg[2*p+0][1]);
            v[1] = cvt2(areg[2*p+0][2], areg[2*p+0][3]);
            v[2] = cvt2(areg[2*p+1][0], areg[2*p+1][1]);
            v[3] = cvt2(areg[2*p+1][2], areg[2*p+1][3]);
            *(u32x4*)&As[(arow + p * 64) * LDA + ak8] = v;
        }
        #pragma unroll
        for (int r = 0; r < 2; ++r) {
            const unsigned w = (unsigned)breg[r];
            float f[8];
            #pragma unroll
            for (int j = 0; j < 8; ++j)
                f[j] = fmaf((float)((w >> (28 - 4*j)) & 15u), sc, nzs);
            u32x4 v;
            v[0] = cvt2(f[0], f[1]);
            v[1] = cvt2(f[2], f[3]);
            v[2] = cvt2(f[4], f[5]);
            v[3] = cvt2(f[6], f[7]);
            *(u32x4*)&Bs[bcol * LDA + (brow0 + 2*r) * 8] = v;
        }
    };

    f32x4 acc[4][4] = {};

    const int wm = (wave >> 1) * 64;
    const int wn = (wave & 1) * 64;
    const int fr = lane & 15;
    const int fq = lane >> 4;

    const short* Abase = &As[(wm + fr) * LDA + fq * 8];
    const short* Bbase = &Bs[(wn + fr) * LDA + fq * 8];

    load_tile(0);
    store_tile();
    __syncthreads();

    for (int kt = 0;;) {
        const int knext = kt + 32;
        const bool last = (knext >= K_DIM);
        if (!last) load_tile(knext);

        short8 af[4], bf[4];
        #pragma unroll
        for (int i = 0; i < 4; ++i) {
            af[i] = *(const short8*)(Abase + i * 16 * LDA);
            bf[i] = *(const short8*)(Bbase + i * 16 * LDA);
        }
        #pragma unroll
        for (int mi = 0; mi < 4; ++mi)
            #pragma unroll
            for (int ni = 0; ni < 4; ++ni)
                acc[mi][ni] = __builtin_amdgcn_mfma_f32_16x16x32_bf16(
                    af[mi], bf[ni], acc[mi][ni], 0, 0, 0);

        if (last) break;
        __syncthreads();
        store_tile();
        __syncthreads();
        kt = knext;
    }

    #pragma unroll
    for (int mi = 0; mi < 4; ++mi) {
        #pragma unroll
        for (int ni = 0; ni < 4; ++ni) {
            const int row = m0 + wm + mi * 16 + fq * 4;
            const int col = n0 + wn + ni * 16 + fr;
            float* cp = C + (size_t)row * N_DIM + col;
            #pragma unroll
            for (int r = 0; r < 4; ++r)
                cp[(size_t)r * N_DIM] = acc[mi][ni][r];
        }
    }
}

extern "C" void kernel_launch(void* const* d_in, const int* in_sizes, int n_in,
                              void* d_out, int out_size, void* d_ws, size_t ws_size,
                              hipStream_t stream) {
    const float* X  = (const float*)d_in[0];
    const int*   Q  = (const int*)d_in[1];
    const float* SC = (const float*)d_in[2];
    const float* ZP = (const float*)d_in[3];
    float*       C  = (float*)d_out;
    (void)in_sizes; (void)n_in; (void)out_size;

    const size_t xb_bytes = (size_t)M_DIM * K_DIM * 2;   // 67,108,864
    const size_t wt_bytes = (size_t)N_DIM * K_DIM * 2;   // 90,177,536

    if (ws_size >= xb_bytes + wt_bytes) {
        u16* Xb = (u16*)d_ws;
        u16* Wt = (u16*)((char*)d_ws + xb_bytes);
        xcvt<<<dim3(M_DIM * K_DIM / (256 * 8)), 256, 0, stream>>>(X, Xb);
        wdeq<<<dim3(N_DIM / 32, K_DIM / 64), 256, 0, stream>>>(Q, SC, ZP, Wt);
        qgemm_main<<<dim3(N_DIM / 128, M_DIM / 128), 256, 0, stream>>>(Xb, Wt, C);
    } else {
        qgemm_fused<<<dim3(N_DIM / 128, M_DIM / 128), 256, 0, stream>>>(X, Q, SC, ZP, C);
    }
}

// Round 2
// 1135.357 us; speedup vs baseline: 1.4721x; 1.4721x over previous
//
#include <hip/hip_runtime.h>
#include <hip/hip_bf16.h>

// QLinear int4-dequant GEMM: C[8192,11008] = X[8192,4096](fp32) @ deq(W)[4096,11008]
// v3: prepasses (X->bf16, W int4->bf16 [n][k]) + 256^2-tile 8-phase counted-vmcnt
//     bf16 GEMM (m201 structure): BK=64, 8 waves (2Mx4N), 512 thr, 128 KiB LDS,
//     global_load_lds w16 staging, raw s_barrier, vmcnt(4) once per K-tile
//     (never drained to 0 in steady state), setprio(1) around MFMA quadrants,
//     bijective XCD swizzle (1376 = 8*172).
// Rationale: v2's __syncthreads() drained vmcnt(0) every BK=32 step -> stage-
// latency-bound (MfmaUtil 25%, VALUBusy 11%). 8-phase counted-vmcnt is the
// proven fix (+28-41% T3/T4, +21-25% T5, +10% T1).

#define K_DIM 4096
#define N_DIM 11008
#define M_DIM 8192
#define NTILE (K_DIM / 64)   // 64 K-tiles of BK=64

typedef unsigned short u16;
typedef __attribute__((ext_vector_type(8))) short short8;       // 8 x bf16 MFMA A/B frag
typedef __attribute__((ext_vector_type(4))) float f32x4;        // MFMA C/D frag / float4
typedef __attribute__((ext_vector_type(4))) unsigned int u32x4; // 16B store of 8 bf16

__device__ __forceinline__ unsigned cvt2(float a, float b) {
    __hip_bfloat162 h = __float22bfloat162_rn(make_float2(a, b));
    unsigned u;
    __builtin_memcpy(&u, &h, 4);
    return u;
}

#define GLOAD_LDS16(g, l)                                                 \
    __builtin_amdgcn_global_load_lds(                                     \
        (const __attribute__((address_space(1))) unsigned int*)(g),       \
        (__attribute__((address_space(3))) unsigned int*)(l), 16, 0, 0)

// ---------------------------------------------------------------------------
// Pre-pass 1: X fp32 -> bf16. 8 floats/thread, fully coalesced.
__global__ __launch_bounds__(256) void xcvt(const float* __restrict__ X,
                                            u16* __restrict__ Xb) {
    const size_t i = ((size_t)blockIdx.x * 256 + threadIdx.x) * 8;
    f32x4 a = *(const f32x4*)(X + i);
    f32x4 b = *(const f32x4*)(X + i + 4);
    u32x4 v;
    v[0] = cvt2(a[0], a[1]);
    v[1] = cvt2(a[2], a[3]);
    v[2] = cvt2(b[0], b[1]);
    v[3] = cvt2(b[2], b[3]);
    *(u32x4*)(Xb + i) = v;
}

// ---------------------------------------------------------------------------
// Pre-pass 2: W int4 -> bf16, layout Wt[n][k] (k-contiguous, GEMM B^T form).
__global__ __launch_bounds__(256) void wdeq(const int* __restrict__ Q,
                                            const float* __restrict__ SC,
                                            const float* __restrict__ ZP,
                                            u16* __restrict__ Wt) {
    const int t  = threadIdx.x;
    const int n  = blockIdx.x * 32 + (t >> 3);
    const int kw = blockIdx.y * 8 + (t & 7);
    const unsigned w = (unsigned)Q[(size_t)kw * N_DIM + n];
    const float sc  = SC[n];
    const float nzs = -ZP[n] * sc;  // exact affine: (float)nib * sc + nzs
    float f[8];
#pragma unroll
    for (int j = 0; j < 8; ++j)  // k = kw*8 + j, nibble j at bits [28-4j..31-4j]
        f[j] = fmaf((float)((w >> (28 - 4 * j)) & 15u), sc, nzs);
    u32x4 v;
    v[0] = cvt2(f[0], f[1]);
    v[1] = cvt2(f[2], f[3]);
    v[2] = cvt2(f[4], f[5]);
    v[3] = cvt2(f[6], f[7]);
    *(u32x4*)(Wt + (size_t)n * K_DIM + kw * 8) = v;
}

// ---------------------------------------------------------------------------
// Main GEMM: 256x256 tile, BK=64, 8 waves (2M x 4N), per-wave 128x64 output
// (8x4 frags of 16x16x32 bf16). LDS: [buf][mat][kh] = 8 regions x 16 KiB,
// region = 256 rows x 32 k (one k-half), rows of 4 16B-units, XOR-swizzled:
// LDS[row][u] holds global k-unit u ^ ((row>>1)&3)  (0-bank-conflict, HW-
// verified round 1). 4 phases per K-tile: (half0,kh0)(half1,kh0)(half0,kh1)
// (half1,kh1); each phase stages 1 half-tile (2 gload_lds) of a future K-tile;
// one vmcnt(4) per K-tile guarantees next K-tile staged, leaving the 2 newest
// half-tiles in flight.
__global__ __launch_bounds__(512, 2) void qgemm_8ph(const u16* __restrict__ Ab,
                                                    const u16* __restrict__ Bt,
                                                    float* __restrict__ C) {
    __shared__ u16 lds[8 * 8192];   // 128 KiB

    const int tid  = threadIdx.x;
    const int lane = tid & 63;
    const int wave = tid >> 6;
    const int wm = wave >> 2;       // 0..1 (M half)
    const int wn = wave & 3;        // 0..3 (N quarter)

    // Bijective XCD swizzle: nwg = 43*32 = 1376 = 8*172
    const int bid = (int)blockIdx.x;
    const int swz = (bid & 7) * 172 + (bid >> 3);
    const int bx = swz % 43;
    const int by = swz / 43;
    const int m0 = by * 256;
    const int n0 = bx * 256;

    // Staging: per issue, 512 thr x 16B = 128 rows x 64B. Linear LDS dest
    // (unit = tid), global source pre-swizzled: unit u=tid&3 of row tid>>2
    // holds global k-unit (tid&3) ^ ((tid>>3)&3).
    const int srow = tid >> 2;
    const int sg   = (tid & 3) ^ ((tid >> 3) & 3);
    const u16* gA = Ab + (size_t)(m0 + srow) * K_DIM + sg * 8;
    const u16* gB = Bt + (size_t)(n0 + srow) * K_DIM + sg * 8;
    u16* ldst = &lds[tid * 8];

    auto stage = [&](int buf, int mat, int kh, int kt) {
        const u16* g = (mat ? gB : gA) + kt * 64 + kh * 32;
        u16* l = ldst + ((buf * 2 + mat) * 2 + kh) * 8192;
        GLOAD_LDS16(g, l);
        GLOAD_LDS16(g + (size_t)128 * K_DIM, l + 4096);  // rows 128..255
    };

    // Fragment reads: row = (wave-slice + frag*16 + fr), unit = fq ^ ((fr>>1)&3)
    const int fr = lane & 15;
    const int fq = lane >> 4;
    const int uo = (fq ^ ((fr >> 1) & 3)) * 8;
    const int aoff = (wm * 128 + fr) * 32 + uo;   // + half*2048 + i*512
    const int boff = (wn * 64 + fr) * 32 + uo;    // + ni*512

    short8 af[4], bf[4];
    f32x4 acc[8][4] = {};

    auto rdA = [&](int buf, int kh, int half) {
        const u16* p = &lds[(buf * 4 + kh) * 8192 + aoff + half * 2048];
#pragma unroll
        for (int i = 0; i < 4; ++i) af[i] = *(const short8*)(p + i * 512);
    };
    auto rdB = [&](int buf, int kh) {
        const u16* p = &lds[((buf * 2 + 1) * 2 + kh) * 8192 + boff];
#pragma unroll
        for (int i = 0; i < 4; ++i) bf[i] = *(const short8*)(p + i * 512);
    };
    auto quad = [&](int half) {   // 16 MFMA: one (M-half x all-N) x one k-step
        __builtin_amdgcn_s_setprio(1);
#pragma unroll
        for (int mi = 0; mi < 4; ++mi)
#pragma unroll
            for (int ni = 0; ni < 4; ++ni)
                acc[half * 4 + mi][ni] = __builtin_amdgcn_mfma_f32_16x16x32_bf16(
                    af[mi], bf[ni], acc[half * 4 + mi][ni], 0, 0, 0);
        __builtin_amdgcn_s_setprio(0);
    };

    // Prologue: T=0 fully + T=1 k-half0 (12 loads); wait leaves the last 4.
    stage(0, 0, 0, 0); stage(0, 1, 0, 0); stage(0, 0, 1, 0); stage(0, 1, 1, 0);
    stage(1, 0, 0, 1); stage(1, 1, 0, 1);
    asm volatile("s_waitcnt vmcnt(4)" ::: "memory");
    __builtin_amdgcn_s_barrier();

    for (int T = 0; T < NTILE; ++T) {
        const int b = T & 1;
        const bool p1 = (T + 1 < NTILE);
        const bool p2 = (T + 2 < NTILE);

        // phase 0: (half0, kh0); stage (T+1).A.kh1 -> other buf
        rdA(b, 0, 0); rdB(b, 0);
        if (p1) stage(b ^ 1, 0, 1, T + 1);
        __builtin_amdgcn_s_barrier();
        quad(0);
        __builtin_amdgcn_s_barrier();

        // phase 1: (half1, kh0), reuse bf; stage (T+1).B.kh1
        rdA(b, 0, 1);
        if (p1) stage(b ^ 1, 1, 1, T + 1);
        __builtin_amdgcn_s_barrier();
        quad(1);
        __builtin_amdgcn_s_barrier();

        // phase 2: (half0, kh1); kh0 of this buf fully consumed -> stage (T+2).A.kh0
        rdA(b, 1, 0); rdB(b, 1);
        if (p2) stage(b, 0, 0, T + 2);
        __builtin_amdgcn_s_barrier();
        quad(0);
        __builtin_amdgcn_s_barrier();

        // phase 3: (half1, kh1); stage (T+2).B.kh0; counted wait: everything
        // through (T+1).B.kh1 complete, 2 newest half-tiles stay in flight.
        rdA(b, 1, 1);
        if (p2) {
            stage(b, 1, 0, T + 2);
            asm volatile("s_waitcnt vmcnt(4)" ::: "memory");
        } else if (p1) {
            asm volatile("s_waitcnt vmcnt(0)" ::: "memory");
        }
        __builtin_amdgcn_s_barrier();
        quad(1);
        __builtin_amdgcn_s_barrier();
    }

    // Epilogue: C/D layout col=lane&15, row=fq*4+r (m89/m91-verified)
#pragma unroll
    for (int mf = 0; mf < 8; ++mf) {
#pragma unroll
        for (int ni = 0; ni < 4; ++ni) {
            const int row = m0 + wm * 128 + mf * 16 + fq * 4;
            const int col = n0 + wn * 64 + ni * 16 + fr;
            float* cp = C + (size_t)row * N_DIM + col;
#pragma unroll
            for (int r = 0; r < 4; ++r)
                cp[(size_t)r * N_DIM] = acc[mf][ni][r];
        }
    }
}

// ---------------------------------------------------------------------------
// Fallback (round-0 verified fused kernel) for ws_size < 157.3 MB.
#define LDA 40
__global__ __launch_bounds__(256, 3) void qgemm_fused(
    const float* __restrict__ X, const int* __restrict__ Q,
    const float* __restrict__ SC, const float* __restrict__ ZP,
    float* __restrict__ C)
{
    __shared__ short As[128 * LDA];
    __shared__ short Bs[128 * LDA];

    const int tid  = threadIdx.x;
    const int lane = tid & 63;
    const int wave = tid >> 6;

    const int m0 = blockIdx.y * 128;
    const int n0 = blockIdx.x * 128;

    const int arow = tid >> 2;
    const int ak8  = (tid & 3) * 8;
    const float* xbase = X + (size_t)(m0 + arow) * K_DIM + ak8;

    const int bcol  = tid & 127;
    const int brow0 = tid >> 7;
    const int* qbase = Q + (size_t)brow0 * N_DIM + n0 + bcol;
    const float sc  = SC[n0 + bcol];
    const float nzs = -ZP[n0 + bcol] * sc;

    f32x4 areg[4];
    int   breg[2];

    auto load_tile = [&](int kt) {
        const float* p0 = xbase + kt;
        areg[0] = *(const f32x4*)(p0);
        areg[1] = *(const f32x4*)(p0 + 4);
        const float* p1 = p0 + (size_t)64 * K_DIM;
        areg[2] = *(const f32x4*)(p1);
        areg[3] = *(const f32x4*)(p1 + 4);
        const int* q0 = qbase + (size_t)(kt >> 3) * N_DIM;
        breg[0] = q0[0];
        breg[1] = q0[2 * N_DIM];
    };

    auto store_tile = [&]() {
        #pragma unroll
        for (int p = 0; p < 2; ++p) {
            u32x4 v;
            v[0] = cvt2(areg[2*p+0][0], areg[2*p+0][1]);
            v[1] = cvt2(areg[2*p+0][2], areg[2*p+0][3]);
            v[2] = cvt2(areg[2*p+1][0], areg[2*p+1][1]);
            v[3] = cvt2(areg[2*p+1][2], areg[2*p+1][3]);
            *(u32x4*)&As[(arow + p * 64) * LDA + ak8] = v;
        }
        #pragma unroll
        for (int r = 0; r < 2; ++r) {
            const unsigned w = (unsigned)breg[r];
            float f[8];
            #pragma unroll
            for (int j = 0; j < 8; ++j)
                f[j] = fmaf((float)((w >> (28 - 4*j)) & 15u), sc, nzs);
            u32x4 v;
            v[0] = cvt2(f[0], f[1]);
            v[1] = cvt2(f[2], f[3]);
            v[2] = cvt2(f[4], f[5]);
            v[3] = cvt2(f[6], f[7]);
            *(u32x4*)&Bs[bcol * LDA + (brow0 + 2*r) * 8] = v;
        }
    };

    f32x4 acc[4][4] = {};

    const int wm = (wave >> 1) * 64;
    const int wn = (wave & 1) * 64;
    const int fr = lane & 15;
    const int fq = lane >> 4;

    const short* Abase = &As[(wm + fr) * LDA + fq * 8];
    const short* Bbase = &Bs[(wn + fr) * LDA + fq * 8];

    load_tile(0);
    store_tile();
    __syncthreads();

    for (int kt = 0;;) {
        const int knext = kt + 32;
        const bool last = (knext >= K_DIM);
        if (!last) load_tile(knext);

        short8 af[4], bf[4];
        #pragma unroll
        for (int i = 0; i < 4; ++i) {
            af[i] = *(const short8*)(Abase + i * 16 * LDA);
            bf[i] = *(const short8*)(Bbase + i * 16 * LDA);
        }
        #pragma unroll
        for (int mi = 0; mi < 4; ++mi)
            #pragma unroll
            for (int ni = 0; ni < 4; ++ni)
                acc[mi][ni] = __builtin_amdgcn_mfma_f32_16x16x32_bf16(
                    af[mi], bf[ni], acc[mi][ni], 0, 0, 0);

        if (last) break;
        __syncthreads();
        store_tile();
        __syncthreads();
        kt = knext;
    }

    #pragma unroll
    for (int mi = 0; mi < 4; ++mi) {
        #pragma unroll
        for (int ni = 0; ni < 4; ++ni) {
            const int row = m0 + wm + mi * 16 + fq * 4;
            const int col = n0 + wn + ni * 16 + fr;
            float* cp = C + (size_t)row * N_DIM + col;
            #pragma unroll
            for (int r = 0; r < 4; ++r)
                cp[(size_t)r * N_DIM] = acc[mi][ni][r];
        }
    }
}

extern "C" void kernel_launch(void* const* d_in, const int* in_sizes, int n_in,
                              void* d_out, int out_size, void* d_ws, size_t ws_size,
                              hipStream_t stream) {
    const float* X  = (const float*)d_in[0];
    const int*   Q  = (const int*)d_in[1];
    const float* SC = (const float*)d_in[2];
    const float* ZP = (const float*)d_in[3];
    float*       C  = (float*)d_out;
    (void)in_sizes; (void)n_in; (void)out_size;

    const size_t xb_bytes = (size_t)M_DIM * K_DIM * 2;   // 67,108,864
    const size_t wt_bytes = (size_t)N_DIM * K_DIM * 2;   // 90,177,536

    if (ws_size >= xb_bytes + wt_bytes) {
        u16* Xb = (u16*)d_ws;
        u16* Wt = (u16*)((char*)d_ws + xb_bytes);
        xcvt<<<dim3(M_DIM * K_DIM / (256 * 8)), 256, 0, stream>>>(X, Xb);
        wdeq<<<dim3(N_DIM / 32, K_DIM / 64), 256, 0, stream>>>(Q, SC, ZP, Wt);
        qgemm_8ph<<<dim3((N_DIM / 256) * (M_DIM / 256)), 512, 0, stream>>>(Xb, Wt, C);
    } else {
        qgemm_fused<<<dim3(N_DIM / 128, M_DIM / 128), 256, 0, stream>>>(X, Q, SC, ZP, C);
    }
}